// Round 1
// baseline (440.044 us; speedup 1.0000x reference)
//
#include <hip/hip_runtime.h>

#define T_LEN   262144
#define NV      20
#define NE      30
#define NH      40
#define NG      160                  // 4*NH
#define CHUNK   512
#define WARM    128
#define SPC     (WARM + CHUNK)       // 640
#define NBLK    (T_LEN / CHUNK)      // 512
#define NTHR    448

__device__ __forceinline__ float sig_(float x) {
    x = fminf(fmaxf(x, -30.f), 30.f);
    return __fdividef(1.f, 1.f + __expf(-x));
}
__device__ __forceinline__ float tanh_(float x) {
    x = fminf(fmaxf(x, -15.f), 15.f);
    float e = __expf(2.f * x);
    return __fdividef(e - 1.f, e + 1.f);
}

extern "C" __global__ void __launch_bounds__(NTHR, 4)
bilstm_kernel(const int* __restrict__ tokens,
              const float* __restrict__ embed,
              const float* __restrict__ W_ih1, const float* __restrict__ W_hh1,
              const float* __restrict__ b_ih1, const float* __restrict__ b_hh1,
              const float* __restrict__ W_ih2, const float* __restrict__ W_hh2,
              const float* __restrict__ b_ih2, const float* __restrict__ b_hh2,
              const float* __restrict__ W_l1,  const float* __restrict__ b_l1,
              const float* __restrict__ W_l2,  const float* __restrict__ b_l2,
              float* __restrict__ out)
{
    __shared__ __align__(16) float table[2][NV * NG];   // x-pre lookup per token
    __shared__ __align__(16) float embS[NV * NE];
    __shared__ __align__(16) float hbuf[2][NH];
    __shared__ __align__(16) float gbuf[2][NG];         // [k*4 + gate]
    __shared__ int tokS[2][SPC];

    const int tid = threadIdx.x;
    const int a   = blockIdx.x * CHUNK;                 // first output row of this chunk

    // ---- stage embed + tokens, zero h ----
    for (int p = tid; p < NV * NE; p += NTHR) embS[p] = embed[p];
    for (int p = tid; p < SPC; p += NTHR) {
        int t = a - WARM + p;
        if (t >= 0) {
            tokS[0][p] = tokens[t];
            tokS[1][p] = tokens[T_LEN - 1 - t];
        }
    }
    if (tid < 2 * NH) ((float*)hbuf)[tid] = 0.f;
    __syncthreads();

    // ---- build X tables: table[d][v*NG+j] = embed[v,:]@W_ih[j,:] + b_ih[j]+b_hh[j] ----
    for (int p = tid; p < 2 * NV * NG; p += NTHR) {
        int d  = p / (NV * NG);
        int r  = p - d * (NV * NG);
        int v  = r / NG;
        int jj = r - v * NG;
        const float* Wih = d ? W_ih2 : W_ih1;
        const float* bi  = d ? b_ih2 : b_ih1;
        const float* bh  = d ? b_hh2 : b_hh1;
        float acc = bi[jj] + bh[jj];
        #pragma unroll
        for (int e = 0; e < NE; ++e) acc += embS[v * NE + e] * Wih[jj * NE + e];
        table[d][v * NG + jj] = acc;
    }

    // ---- thread roles ----
    const bool isGate = (tid < NG) || (tid >= 192 && tid < 192 + NG);
    const int  gdir   = (tid < NG) ? 0 : 1;
    const int  j      = isGate ? ((tid < NG) ? tid : tid - 192) : 0;
    const int  ggate  = j / NH;            // 0:i 1:f 2:g 3:o
    const int  kk     = j - ggate * NH;

    const int  ll      = tid - 384;        // wave 6 = logits
    const bool isLWave = (tid >= 384);
    const int  lhalf   = isLWave ? ((ll >> 5) & 1) : 0;
    const int  lv      = isLWave ? (ll & 31) : 0;
    const bool doLogit = isLWave && (lv < NV);

    // wreg: W_hh row for gate threads, W_l row for logit threads (disjoint)
    float wreg[NH];
    float lb = 0.f;
    if (isGate) {
        const float* Whh = gdir ? W_hh2 : W_hh1;
        const float4* wr = (const float4*)(Whh + j * NH);
        #pragma unroll
        for (int q = 0; q < NH / 4; ++q) {
            float4 t4 = wr[q];
            wreg[4*q+0]=t4.x; wreg[4*q+1]=t4.y; wreg[4*q+2]=t4.z; wreg[4*q+3]=t4.w;
        }
    } else if (doLogit) {
        const float* Wl = lhalf ? W_l2 : W_l1;
        const float4* wr = (const float4*)(Wl + lv * NH);
        #pragma unroll
        for (int q = 0; q < NH / 4; ++q) {
            float4 t4 = wr[q];
            wreg[4*q+0]=t4.x; wreg[4*q+1]=t4.y; wreg[4*q+2]=t4.z; wreg[4*q+3]=t4.w;
        }
        if (lhalf == 0) lb = b_l1[lv] + b_l2[lv];
    }
    __syncthreads();   // tables/tokens ready

    const int s_begin = (a >= WARM) ? 0 : (WARM - a);
    float c = 0.f;
    float x_pre = 0.f;
    if (isGate) {
        int tk = tokS[gdir][s_begin];
        x_pre = table[gdir][tk * NG + j];
    }

    for (int s = s_begin; s <= SPC; ++s) {
        const bool doStep = (s < SPC);

        // ---- phase 1: gate pre-acts + activations; logits for previous step ----
        if (isGate && doStep) {
            const float4* h4 = (const float4*)hbuf[gdir];
            float a0 = x_pre, a1 = 0.f, a2 = 0.f, a3 = 0.f;
            #pragma unroll
            for (int q = 0; q < NH / 4; ++q) {
                float4 hv = h4[q];
                a0 += hv.x * wreg[4*q+0];
                a1 += hv.y * wreg[4*q+1];
                a2 += hv.z * wreg[4*q+2];
                a3 += hv.w * wreg[4*q+3];
            }
            float g   = (a0 + a1) + (a2 + a3);
            float act = (ggate == 2) ? tanh_(g) : sig_(g);
            gbuf[gdir][kk * 4 + ggate] = act;
        }
        if (doLogit && s > WARM) {   // h of step (s-1) still in hbuf
            const float4* h4 = (const float4*)hbuf[lhalf];
            float acc = 0.f;
            #pragma unroll
            for (int q = 0; q < NH / 4; ++q) {
                float4 hv = h4[q];
                acc += hv.x*wreg[4*q+0] + hv.y*wreg[4*q+1]
                     + hv.z*wreg[4*q+2] + hv.w*wreg[4*q+3];
            }
            float other = __shfl_xor(acc, 32, 64);
            if (lhalf == 0) {
                int tprev = a - WARM + s - 1;
                out[(size_t)tprev * NV + lv] = acc + other + lb;
            }
        }
        __syncthreads();

        // ---- phase 2: prefetch next x; combine gates -> c,h ----
        if (isGate && doStep) {
            if (s + 1 < SPC) {
                int tk = tokS[gdir][s + 1];
                x_pre = table[gdir][tk * NG + j];
            }
            if (j < NH) {   // combine threads: j == k
                float4 g4 = ((const float4*)gbuf[gdir])[j];   // i,f,g,o
                c = g4.y * c + g4.x * g4.z;
                hbuf[gdir][j] = g4.w * tanh_(c);
            }
        }
        __syncthreads();
    }
}

extern "C" void kernel_launch(void* const* d_in, const int* in_sizes, int n_in,
                              void* d_out, int out_size, void* d_ws, size_t ws_size,
                              hipStream_t stream)
{
    const int*   tokens = (const int*)  d_in[0];
    const float* embed  = (const float*)d_in[1];
    const float* W_ih1  = (const float*)d_in[2];
    const float* W_hh1  = (const float*)d_in[3];
    const float* b_ih1  = (const float*)d_in[4];
    const float* b_hh1  = (const float*)d_in[5];
    const float* W_ih2  = (const float*)d_in[6];
    const float* W_hh2  = (const float*)d_in[7];
    const float* b_ih2  = (const float*)d_in[8];
    const float* b_hh2  = (const float*)d_in[9];
    const float* W_l1   = (const float*)d_in[10];
    const float* b_l1   = (const float*)d_in[11];
    const float* W_l2   = (const float*)d_in[12];
    const float* b_l2   = (const float*)d_in[13];
    float* out = (float*)d_out;

    hipLaunchKernelGGL(bilstm_kernel, dim3(NBLK), dim3(NTHR), 0, stream,
                       tokens, embed, W_ih1, W_hh1, b_ih1, b_hh1,
                       W_ih2, W_hh2, b_ih2, b_hh2, W_l1, b_l1, W_l2, b_l2, out);
}